// Round 6
// baseline (14.016 us; speedup 1.0000x reference)
//
#include <hip/hip_runtime.h>
#include <hip/hip_bf16.h>

// Tropical linear: out[r,o] = logsumexp_i(x[r,i] + w[i,o]) = log( sum_i exp(x[r,i]) * exp(w[i,o]) )
// R6 = R5 + DIAGNOSTIC second body: after writing out, each block re-runs the identical
// tile pipeline on a cold 8MB d_ws region (read-only, poison-constant -> deterministic)
// and writes to a disjoint d_ws region. Reuses the LDS exp(w) fragments (no 2nd barrier).
// Purpose: dur_new - dur_old = marginal cost of one kernel body, separating fixed
// launch/graph overhead from body time. d_out is written only by phase 1.

using bf16x8 = __attribute__((ext_vector_type(8))) short;   // 8 bf16 = 4 VGPRs
using f32x4  = __attribute__((ext_vector_type(4))) float;   // MFMA accumulator

__device__ __forceinline__ unsigned short f2bf(float v) {
    __hip_bfloat16 b = __float2bfloat16(v);
    return __builtin_bit_cast(unsigned short, b);
}

__global__ __launch_bounds__(256) void trop_kernel(const float* __restrict__ x,
                                                   const float* __restrict__ w,
                                                   float* __restrict__ out,
                                                   const float* __restrict__ x2,
                                                   float* __restrict__ out2) {
    // B(=exp(w)) fragments for THIS block's 64 cols: f_loc = cc*4 + kb
    __shared__ uint4 ewl[1024];  // 16 frags * 64 slots * 16B = 16 KiB

    const int tid  = threadIdx.x;
    const int lane = tid & 63;
    const int wv   = tid >> 6;        // 0..3 = row strip within block
    const int r16  = lane & 15;
    const int g    = lane >> 4;       // 0..3

    const int r0   = blockIdx.x * 64 + wv * 16;  // wave's first row
    const int c0   = blockIdx.y * 64;            // block's first col
    const int grow = r0 + r16;

    // ---- phase 1: identical to R5 ----
    const float* xp = x + (size_t)grow * 128 + g * 8;
    float4 xv[8];
#pragma unroll
    for (int kb = 0; kb < 4; ++kb) {
#pragma unroll
        for (int h = 0; h < 2; ++h)
            xv[kb * 2 + h] = *reinterpret_cast<const float4*>(xp + kb * 32 + h * 4);
    }

#pragma unroll
    for (int r = 0; r < 4; ++r) {
        int s  = r * 256 + tid;
        int f  = s >> 6;
        int L  = s & 63;
        int kb = f & 3;
        int cc = f >> 2;
        int o  = c0 + cc * 16 + (L & 15);
        const float* wp = w + (size_t)(kb * 32 + (L >> 4) * 8) * 128 + o;
        unsigned int pk[4];
#pragma unroll
        for (int e = 0; e < 4; ++e) {
            unsigned short lo = f2bf(__expf(wp[(2 * e)     * 128]));
            unsigned short hi = f2bf(__expf(wp[(2 * e + 1) * 128]));
            pk[e] = (unsigned int)lo | ((unsigned int)hi << 16);
        }
        ewl[f * 64 + L] = make_uint4(pk[0], pk[1], pk[2], pk[3]);
    }

    bf16x8 afrag[4];
#pragma unroll
    for (int kb = 0; kb < 4; ++kb) {
#pragma unroll
        for (int h = 0; h < 2; ++h) {
            float4 v = xv[kb * 2 + h];
            afrag[kb][h * 4 + 0] = (short)f2bf(__expf(v.x));
            afrag[kb][h * 4 + 1] = (short)f2bf(__expf(v.y));
            afrag[kb][h * 4 + 2] = (short)f2bf(__expf(v.z));
            afrag[kb][h * 4 + 3] = (short)f2bf(__expf(v.w));
        }
    }

    __syncthreads();

    f32x4 acc[4] = {};
#pragma unroll
    for (int kb = 0; kb < 4; ++kb) {
#pragma unroll
        for (int cc = 0; cc < 4; ++cc) {
            bf16x8 b = *reinterpret_cast<const bf16x8*>(&ewl[(cc * 4 + kb) * 64 + lane]);
            acc[cc] = __builtin_amdgcn_mfma_f32_16x16x32_bf16(afrag[kb], b, acc[cc], 0, 0, 0);
        }
    }

#pragma unroll
    for (int cc = 0; cc < 4; ++cc) {
        int col = c0 + cc * 16 + r16;
        float* op = out + (size_t)(r0 + g * 4) * 128 + col;
#pragma unroll
        for (int q = 0; q < 4; ++q)
            op[(size_t)q * 128] = __logf(acc[cc][q]);
    }

    // ---- phase 2 (DIAGNOSTIC): identical body on cold d_ws data, reusing ewl ----
    const float* xp2 = x2 + (size_t)grow * 128 + g * 8;
    float4 yv[8];
#pragma unroll
    for (int kb = 0; kb < 4; ++kb) {
#pragma unroll
        for (int h = 0; h < 2; ++h)
            yv[kb * 2 + h] = *reinterpret_cast<const float4*>(xp2 + kb * 32 + h * 4);
    }

    bf16x8 afrag2[4];
#pragma unroll
    for (int kb = 0; kb < 4; ++kb) {
#pragma unroll
        for (int h = 0; h < 2; ++h) {
            float4 v = yv[kb * 2 + h];
            afrag2[kb][h * 4 + 0] = (short)f2bf(__expf(v.x));
            afrag2[kb][h * 4 + 1] = (short)f2bf(__expf(v.y));
            afrag2[kb][h * 4 + 2] = (short)f2bf(__expf(v.z));
            afrag2[kb][h * 4 + 3] = (short)f2bf(__expf(v.w));
        }
    }

    f32x4 acc2[4] = {};
#pragma unroll
    for (int kb = 0; kb < 4; ++kb) {
#pragma unroll
        for (int cc = 0; cc < 4; ++cc) {
            bf16x8 b = *reinterpret_cast<const bf16x8*>(&ewl[(cc * 4 + kb) * 64 + lane]);
            acc2[cc] = __builtin_amdgcn_mfma_f32_16x16x32_bf16(afrag2[kb], b, acc2[cc], 0, 0, 0);
        }
    }

#pragma unroll
    for (int cc = 0; cc < 4; ++cc) {
        int col = c0 + cc * 16 + r16;
        float* op = out2 + (size_t)(r0 + g * 4) * 128 + col;
#pragma unroll
        for (int q = 0; q < 4; ++q)
            op[(size_t)q * 128] = __logf(acc2[cc][q]);
    }
}

extern "C" void kernel_launch(void* const* d_in, const int* in_sizes, int n_in,
                              void* d_out, int out_size, void* d_ws, size_t ws_size,
                              hipStream_t stream) {
    const float* x = (const float*)d_in[0];   // [8,2048,128] fp32
    const float* w = (const float*)d_in[1];   // [128,128] fp32
    float* out = (float*)d_out;               // [8,2048,128] fp32
    // d_ws (~268MB): write region = floats [0, 2M); cold read region = floats [4M, 6M)
    // (read region is never written -> poison-constant -> deterministic).
    float* wsOut = (float*)d_ws;
    const float* wsIn = (const float*)d_ws + (4u << 20);
    trop_kernel<<<dim3(256, 2), 256, 0, stream>>>(x, w, out, wsIn, wsOut);
}

// Round 7
// 10.673 us; speedup vs baseline: 1.3133x; 1.3133x over previous
//
#include <hip/hip_runtime.h>
#include <hip/hip_bf16.h>

// Tropical linear: out[r,o] = logsumexp_i(x[r,i] + w[i,o]) = log( sum_i exp(x[r,i]) * exp(w[i,o]) )
// Single kernel, bf16 MFMA GEMM [16384x128]x[128x128] with exp pre- and log post-processing.
// Final structure (best measured, R5): two independent 256-thread blocks per CU
// (decoupled barrier domains). Grid (256,2): block = 64 rows x 64 cols. Blocks
// (bx,0)/(bx,1) are 256 apart in dispatch order -> same XCD -> x shared via L2.
//
// Measured decomposition (R6 body-doubling diagnostic): dur_us ~= 7.4 us fixed
// graph/replay overhead + ~3.3 us body; body moves 16.8 MB -> within ~25% of the
// 6.3 TB/s achievable streaming ceiling. Roofline-bound at the body level.

using bf16x8 = __attribute__((ext_vector_type(8))) short;   // 8 bf16 = 4 VGPRs
using f32x4  = __attribute__((ext_vector_type(4))) float;   // MFMA accumulator

__device__ __forceinline__ unsigned short f2bf(float v) {
    __hip_bfloat16 b = __float2bfloat16(v);
    return __builtin_bit_cast(unsigned short, b);
}

__global__ __launch_bounds__(256) void trop_kernel(const float* __restrict__ x,
                                                   const float* __restrict__ w,
                                                   float* __restrict__ out) {
    // B(=exp(w)) fragments for THIS block's 64 cols: f_loc = cc*4 + kb
    // (cc: local 16-col group 0..3, kb: 32-k group 0..3)
    // slot L holds B[kb*32 + (L>>4)*8 + e][col(cc)*16 + (L&15)], e=0..7, bf16 k-pairs.
    // Fragment-contiguous: writer & reader both consecutive-lane 16B -> 0 bank conflicts.
    __shared__ uint4 ewl[1024];  // 16 frags * 64 slots * 16B = 16 KiB

    const int tid  = threadIdx.x;
    const int lane = tid & 63;
    const int wv   = tid >> 6;        // 0..3 = row strip within block
    const int r16  = lane & 15;
    const int g    = lane >> 4;       // 0..3

    const int r0   = blockIdx.x * 64 + wv * 16;  // wave's first row
    const int c0   = blockIdx.y * 64;            // block's first col
    const int grow = r0 + r16;

    // ---- issue x loads first (the HBM bulk): k = kb*32 + g*8 + {0..7} ----
    const float* xp = x + (size_t)grow * 128 + g * 8;
    float4 xv[8];
#pragma unroll
    for (int kb = 0; kb < 4; ++kb) {
#pragma unroll
        for (int h = 0; h < 2; ++h)
            xv[kb * 2 + h] = *reinterpret_cast<const float4*>(xp + kb * 32 + h * 4);
    }

    // ---- B prep (overlaps x-load latency): exp(w) -> LDS fragments, 4 slots/thread ----
#pragma unroll
    for (int r = 0; r < 4; ++r) {
        int s  = r * 256 + tid;      // slot 0..1023
        int f  = s >> 6;             // local frag 0..15
        int L  = s & 63;
        int kb = f & 3;
        int cc = f >> 2;
        int o  = c0 + cc * 16 + (L & 15);
        const float* wp = w + (size_t)(kb * 32 + (L >> 4) * 8) * 128 + o;
        unsigned int pk[4];
#pragma unroll
        for (int e = 0; e < 4; ++e) {
            unsigned short lo = f2bf(__expf(wp[(2 * e)     * 128]));
            unsigned short hi = f2bf(__expf(wp[(2 * e + 1) * 128]));
            pk[e] = (unsigned int)lo | ((unsigned int)hi << 16);
        }
        ewl[f * 64 + L] = make_uint4(pk[0], pk[1], pk[2], pk[3]);
    }

    // ---- A prep (pre-barrier, hides in barrier skew): exp(x), pack bf16 ----
    bf16x8 afrag[4];
#pragma unroll
    for (int kb = 0; kb < 4; ++kb) {
#pragma unroll
        for (int h = 0; h < 2; ++h) {
            float4 v = xv[kb * 2 + h];
            afrag[kb][h * 4 + 0] = (short)f2bf(__expf(v.x));
            afrag[kb][h * 4 + 1] = (short)f2bf(__expf(v.y));
            afrag[kb][h * 4 + 2] = (short)f2bf(__expf(v.z));
            afrag[kb][h * 4 + 3] = (short)f2bf(__expf(v.w));
        }
    }

    __syncthreads();

    // ---- GEMM: 16 x v_mfma_f32_16x16x32_bf16 per wave (16 rows x 64 cols, K=128) ----
    f32x4 acc[4] = {};
#pragma unroll
    for (int kb = 0; kb < 4; ++kb) {
#pragma unroll
        for (int cc = 0; cc < 4; ++cc) {
            bf16x8 b = *reinterpret_cast<const bf16x8*>(&ewl[(cc * 4 + kb) * 64 + lane]);
            acc[cc] = __builtin_amdgcn_mfma_f32_16x16x32_bf16(afrag[kb], b, acc[cc], 0, 0, 0);
        }
    }

    // ---- epilogue: out = log(sum). C/D: col = lane&15, row = g*4 + reg ----
#pragma unroll
    for (int cc = 0; cc < 4; ++cc) {
        int col = c0 + cc * 16 + r16;
        float* op = out + (size_t)(r0 + g * 4) * 128 + col;
#pragma unroll
        for (int q = 0; q < 4; ++q)
            op[(size_t)q * 128] = __logf(acc[cc][q]);
    }
}

extern "C" void kernel_launch(void* const* d_in, const int* in_sizes, int n_in,
                              void* d_out, int out_size, void* d_ws, size_t ws_size,
                              hipStream_t stream) {
    const float* x = (const float*)d_in[0];   // [8,2048,128] fp32
    const float* w = (const float*)d_in[1];   // [128,128] fp32
    float* out = (float*)d_out;               // [8,2048,128] fp32
    // 256 row-strips x 2 col-halves = 512 blocks of 256 threads; exactly 2 blocks/CU,
    // all co-resident; (bx,0) and (bx,1) share x via same-XCD L2.
    trop_kernel<<<dim3(256, 2), 256, 0, stream>>>(x, w, out);
}